// Round 5
// baseline (165.889 us; speedup 1.0000x reference)
//
#include <hip/hip_runtime.h>

#define D 32

// ---------------------------------------------------------------------------
// Kernel 1: Y[r][:] = X[r][:] @ W (f32) for r < n;  Y[n][:] = 0.
// Two rows per wave (half-wave each), float4 vector loads of the X row,
// W column held in registers (lane j holds W[:,j]).
// ---------------------------------------------------------------------------
__global__ __launch_bounds__(256, 8)
void xw_kernel(const float* __restrict__ X, const float* __restrict__ W,
               float* __restrict__ Y, int n) {
    const int lane = threadIdx.x & 63;
    const int j    = lane & 31;     // output feature
    const int h    = lane >> 5;     // which row of the pair
    const int wid  = (blockIdx.x * blockDim.x + threadIdx.x) >> 6;
    const int nw   = (gridDim.x * blockDim.x) >> 6;

    float w[D];
    #pragma unroll
    for (int d = 0; d < D; ++d) w[d] = W[d * D + j];

    for (int r0 = 2 * wid; r0 <= n; r0 += 2 * nw) {
        const int r = r0 + h;
        float o = 0.f;
        if (r < n) {
            const float4* xr = (const float4*)(X + (size_t)r * D);
            #pragma unroll
            for (int k = 0; k < 8; ++k) {
                float4 xv = xr[k];
                o = fmaf(xv.x, w[4 * k    ], o);
                o = fmaf(xv.y, w[4 * k + 1], o);
                o = fmaf(xv.z, w[4 * k + 2], o);
                o = fmaf(xv.w, w[4 * k + 3], o);
            }
        }
        if (r <= n) Y[(size_t)r * D + j] = o;   // row n -> zeros (harmless)
    }
}

// ---------------------------------------------------------------------------
// Kernel 2: out[r][:] = sum_{e in row r} Y[ci[e]][:]
// Wave = 8 rows; 8-lane group g owns row, lane slot s owns 16B of the row.
// Serial edge loop per group (unroll 4 for VMEM depth). ZERO cross-lane ops:
// no shuffles, no reduce, coalesced 1KB wave store. Finished groups issue no
// loads (exec-masked divergent loop).
// ---------------------------------------------------------------------------
__global__ __launch_bounds__(256, 8)
void agg_kernel(const float* __restrict__ Y, const int* __restrict__ rp,
                const int* __restrict__ ci, float* __restrict__ out, int n) {
    const int lane = threadIdx.x & 63;
    const int g    = lane >> 3;     // row group 0..7
    const int s    = lane & 7;      // float4 slot 0..7
    const int wid  = (blockIdx.x * blockDim.x + threadIdx.x) >> 6;

    const int r = wid * 8 + g;
    if (r >= n) return;

    const int start = rp[r];
    const int deg   = rp[r + 1] - start;
    const int* cp   = ci + start;

    float4 acc = make_float4(0.f, 0.f, 0.f, 0.f);

    int t = 0;
    for (; t + 4 <= deg; t += 4) {
        // 4 edge indices from a streamed (L1-hot) line; 8 lanes/group share
        int c0 = cp[t], c1 = cp[t + 1], c2 = cp[t + 2], c3 = cp[t + 3];
        float4 x0 = ((const float4*)(Y + (size_t)(unsigned)c0 * D))[s];
        float4 x1 = ((const float4*)(Y + (size_t)(unsigned)c1 * D))[s];
        float4 x2 = ((const float4*)(Y + (size_t)(unsigned)c2 * D))[s];
        float4 x3 = ((const float4*)(Y + (size_t)(unsigned)c3 * D))[s];
        acc.x += (x0.x + x1.x) + (x2.x + x3.x);
        acc.y += (x0.y + x1.y) + (x2.y + x3.y);
        acc.z += (x0.z + x1.z) + (x2.z + x3.z);
        acc.w += (x0.w + x1.w) + (x2.w + x3.w);
    }
    for (; t < deg; ++t) {
        int c = cp[t];
        float4 x = ((const float4*)(Y + (size_t)(unsigned)c * D))[s];
        acc.x += x.x; acc.y += x.y; acc.z += x.z; acc.w += x.w;
    }

    // lane (g,s) -> out[r][4s..4s+3]; whole wave = 1KB contiguous store
    ((float4*)(out + (size_t)r * D))[s] = acc;
}

// ---------------------------------------------------------------------------
// Legacy fused kernel (fallback if workspace is too small for Y)
// ---------------------------------------------------------------------------
__global__ __launch_bounds__(256, 4)
void gin_fused(const float* __restrict__ X,
               const float* __restrict__ W,
               const int* __restrict__ rp,
               const int* __restrict__ ci,
               float* __restrict__ out,
               int n) {
    __shared__ float Wl[D * D];

    int tid = threadIdx.x;
    {
        const float4* Wv = (const float4*)W;
        float4* Wlv = (float4*)Wl;
        Wlv[tid] = Wv[tid];
    }
    __syncthreads();

    int wave = tid >> 6;
    int lane = tid & 63;
    int row = blockIdx.x * 4 + wave;
    if (row >= n) return;

    int start = rp[row];
    int deg   = rp[row + 1] - start;

    int g = lane >> 3;
    int s = lane & 7;

    float4 acc = make_float4(0.f, 0.f, 0.f, 0.f);

    for (int cb = 0; cb < deg; cb += 64) {
        int rem = deg - cb;
        int nv  = rem < 64 ? rem : 64;
        int myci = (lane < nv) ? ci[start + cb + lane] : 0;
        {
            float4 x[4]; float m[4];
            #pragma unroll
            for (int it = 0; it < 4; ++it) {
                int l = it * 8 + g;
                int c = __shfl(myci, l, 64);
                m[it] = (l < rem) ? 1.f : 0.f;
                x[it] = ((const float4*)(X + (size_t)c * D))[s];
            }
            #pragma unroll
            for (int it = 0; it < 4; ++it) {
                acc.x = fmaf(m[it], x[it].x, acc.x);
                acc.y = fmaf(m[it], x[it].y, acc.y);
                acc.z = fmaf(m[it], x[it].z, acc.z);
                acc.w = fmaf(m[it], x[it].w, acc.w);
            }
        }
        if (rem > 32) {
            float4 x[4]; float m[4];
            #pragma unroll
            for (int it = 0; it < 4; ++it) {
                int l = (it + 4) * 8 + g;
                int c = __shfl(myci, l, 64);
                m[it] = (l < rem) ? 1.f : 0.f;
                x[it] = ((const float4*)(X + (size_t)c * D))[s];
            }
            #pragma unroll
            for (int it = 0; it < 4; ++it) {
                acc.x = fmaf(m[it], x[it].x, acc.x);
                acc.y = fmaf(m[it], x[it].y, acc.y);
                acc.z = fmaf(m[it], x[it].z, acc.z);
                acc.w = fmaf(m[it], x[it].w, acc.w);
            }
        }
    }

    #pragma unroll
    for (int off = 8; off < 64; off <<= 1) {
        acc.x += __shfl_xor(acc.x, off, 64);
        acc.y += __shfl_xor(acc.y, off, 64);
        acc.z += __shfl_xor(acc.z, off, 64);
        acc.w += __shfl_xor(acc.w, off, 64);
    }

    int j = lane & 31;
    float o = 0.f;
    #pragma unroll
    for (int sg = 0; sg < 8; ++sg) {
        float ax = __shfl(acc.x, sg, 64);
        float ay = __shfl(acc.y, sg, 64);
        float az = __shfl(acc.z, sg, 64);
        float aw = __shfl(acc.w, sg, 64);
        int d = 4 * sg;
        o = fmaf(ax, Wl[(d    ) * D + j], o);
        o = fmaf(ay, Wl[(d + 1) * D + j], o);
        o = fmaf(az, Wl[(d + 2) * D + j], o);
        o = fmaf(aw, Wl[(d + 3) * D + j], o);
    }
    if (lane < 32) out[(size_t)row * D + j] = o;
}

extern "C" void kernel_launch(void* const* d_in, const int* in_sizes, int n_in,
                              void* d_out, int out_size, void* d_ws, size_t ws_size,
                              hipStream_t stream) {
    const float* X  = (const float*)d_in[0];
    const float* W  = (const float*)d_in[1];
    const int*   rp = (const int*)d_in[2];
    const int*   ci = (const int*)d_in[3];
    float* out = (float*)d_out;

    int n = in_sizes[2] - 1;                          // N nodes
    size_t ybytes = (size_t)(n + 1) * D * sizeof(float);

    if (ws_size >= ybytes) {
        float* Y = (float*)d_ws;
        hipLaunchKernelGGL(xw_kernel, dim3(2048), dim3(256), 0, stream,
                           X, W, Y, n);
        int blocks = (n + 31) / 32;                   // 32 rows per block
        hipLaunchKernelGGL(agg_kernel, dim3(blocks), dim3(256), 0, stream,
                           Y, rp, ci, out, n);
    } else {
        hipLaunchKernelGGL(gin_fused, dim3((n + 3) / 4), dim3(256), 0, stream,
                           X, W, rp, ci, out, n);
    }
}

// Round 6
// 128.360 us; speedup vs baseline: 1.2924x; 1.2924x over previous
//
#include <hip/hip_runtime.h>

#define D 32

// ---------------------------------------------------------------------------
// Kernel 1: Y[r][:] = X[r][:] @ W (f32) for r < n;  Y[n][:] = 0 (zero row).
// LDS-tiled: 32 rows per block. Coalesced float4 staging of X-tile and W,
// per-thread output float4 from LDS broadcasts, coalesced float4 store.
// Xl padded to stride 36 floats: rows stay 16B-aligned and banks spread
// (bank = 4*row + d within a wave -> conflict-free broadcast reads).
// ---------------------------------------------------------------------------
__global__ __launch_bounds__(256, 8)
void xw_kernel(const float* __restrict__ X, const float* __restrict__ W,
               float* __restrict__ Y, int n) {
    __shared__ float Xl[32][36];
    __shared__ float Wl[32][32];

    const int tid = threadIdx.x;
    const int row = tid >> 3;      // 0..31
    const int s   = tid & 7;       // float4 slot 0..7

    // stage W (4 KB): thread t -> float4 #t, fully coalesced
    {
        float4 wv = ((const float4*)W)[tid];
        *(float4*)&Wl[tid >> 3][(tid & 7) * 4] = wv;
    }

    const int r = blockIdx.x * 32 + row;   // may equal n (zero row)
    {
        float4 xv = make_float4(0.f, 0.f, 0.f, 0.f);
        if (r < n) xv = ((const float4*)(X + (size_t)r * D))[s];
        *(float4*)&Xl[row][s * 4] = xv;
    }
    __syncthreads();

    float4 a = make_float4(0.f, 0.f, 0.f, 0.f);
    #pragma unroll
    for (int d = 0; d < D; ++d) {
        float  x  = Xl[row][d];                       // broadcast, no conflict
        float4 wv = *(const float4*)&Wl[d][s * 4];    // broadcast, no conflict
        a.x = fmaf(x, wv.x, a.x);
        a.y = fmaf(x, wv.y, a.y);
        a.z = fmaf(x, wv.z, a.z);
        a.w = fmaf(x, wv.w, a.w);
    }
    if (r <= n) ((float4*)(Y + (size_t)r * D))[s] = a;   // r==n -> zeros
}

// ---------------------------------------------------------------------------
// Kernel 2 (round-2 best structure, verbatim): out[r][:] = sum Y[ci[e]][:]
// Wave = 1 row; lane (g,s): g = edge subgroup 0..7, s = float4 slot 0..7.
// 8-granular wave-uniform ladder, zero-row gather for invalid slots,
// persistent waves with 1-deep cross-row rp/ci prefetch.
// ---------------------------------------------------------------------------
template <int K>
__device__ __forceinline__ void gather_acc(const float* __restrict__ Y,
                                           int myci, int base, int g, int s,
                                           float4& acc) {
    float4 x[K];
    #pragma unroll
    for (int it = 0; it < K; ++it) {
        int c = __shfl(myci, (base + it) * 8 + g, 64);   // zrow for invalid
        x[it] = ((const float4*)(Y + (size_t)(unsigned)c * D))[s];
    }
    #pragma unroll
    for (int it = 0; it < K; ++it) {
        acc.x += x[it].x; acc.y += x[it].y;
        acc.z += x[it].z; acc.w += x[it].w;
    }
}

__device__ __forceinline__ void ladder(const float* __restrict__ Y, int myci,
                                       int nv, int g, int s, float4& acc) {
    switch ((nv + 7) >> 3) {            // wave-uniform branch ladder, nv >= 1
        case 1: gather_acc<1>(Y, myci, 0, g, s, acc); break;
        case 2: gather_acc<2>(Y, myci, 0, g, s, acc); break;
        case 3: gather_acc<3>(Y, myci, 0, g, s, acc); break;
        case 4: gather_acc<4>(Y, myci, 0, g, s, acc); break;
        case 5: gather_acc<4>(Y, myci, 0, g, s, acc);
                gather_acc<1>(Y, myci, 4, g, s, acc); break;
        case 6: gather_acc<4>(Y, myci, 0, g, s, acc);
                gather_acc<2>(Y, myci, 4, g, s, acc); break;
        case 7: gather_acc<4>(Y, myci, 0, g, s, acc);
                gather_acc<3>(Y, myci, 4, g, s, acc); break;
        default: gather_acc<4>(Y, myci, 0, g, s, acc);
                 gather_acc<4>(Y, myci, 4, g, s, acc); break;
    }
}

__global__ __launch_bounds__(256, 8)
void agg_kernel(const float* __restrict__ Y, const int* __restrict__ rp,
                const int* __restrict__ ci, float* __restrict__ out, int n) {
    const int lane = threadIdx.x & 63;
    const int g  = lane >> 3;   // edge sub-group 0..7
    const int s  = lane & 7;    // float4 slot 0..7
    const int zr = n;           // zero row index

    const int wid = (blockIdx.x * blockDim.x + threadIdx.x) >> 6;
    const int nw  = (gridDim.x * blockDim.x) >> 6;

    int r = __builtin_amdgcn_readfirstlane(wid);
    if (r >= n) return;

    int start = rp[r];
    int end   = rp[r + 1];
    int nv0   = end - start; nv0 = nv0 > 64 ? 64 : nv0;
    int myci  = (lane < nv0) ? ci[start + lane] : zr;

    while (true) {
        const int deg = end - start;
        const int rn  = r + nw;
        const bool has_next = rn < n;

        // issue NEXT row's pointer+index loads first (latency hides here)
        int nstart = 0, nend = 0, next_ci = zr;
        if (has_next) {
            nstart = rp[rn];
            nend   = rp[rn + 1];
            int nnv = nend - nstart; nnv = nnv > 64 ? 64 : nnv;
            next_ci = (lane < nnv) ? ci[nstart + lane] : zr;
        }

        float4 acc = make_float4(0.f, 0.f, 0.f, 0.f);
        if (deg > 0) {
            int nv = deg > 64 ? 64 : deg;
            ladder(Y, myci, nv, g, s, acc);
            for (int cb = 64; cb < deg; cb += 64) {     // rare tail (~8%)
                int rem = deg - cb;
                int nv2 = rem > 64 ? 64 : rem;
                int c2  = (lane < nv2) ? ci[start + cb + lane] : zr;
                ladder(Y, c2, nv2, g, s, acc);
            }
        }

        // reduce across the 8 edge groups (xor over g bits: 8, 16, 32)
        #pragma unroll
        for (int off = 8; off < 64; off <<= 1) {
            acc.x += __shfl_xor(acc.x, off, 64);
            acc.y += __shfl_xor(acc.y, off, 64);
            acc.z += __shfl_xor(acc.z, off, 64);
            acc.w += __shfl_xor(acc.w, off, 64);
        }
        if (lane < 8) ((float4*)(out + (size_t)r * D))[s] = acc;

        if (!has_next) break;
        r = rn; start = nstart; end = nend; myci = next_ci;
    }
}

// ---------------------------------------------------------------------------
// Legacy fused kernel (fallback if workspace is too small for Y)
// ---------------------------------------------------------------------------
__global__ __launch_bounds__(256, 4)
void gin_fused(const float* __restrict__ X,
               const float* __restrict__ W,
               const int* __restrict__ rp,
               const int* __restrict__ ci,
               float* __restrict__ out,
               int n) {
    __shared__ float Wl[D * D];

    int tid = threadIdx.x;
    {
        const float4* Wv = (const float4*)W;
        float4* Wlv = (float4*)Wl;
        Wlv[tid] = Wv[tid];
    }
    __syncthreads();

    int wave = tid >> 6;
    int lane = tid & 63;
    int row = blockIdx.x * 4 + wave;
    if (row >= n) return;

    int start = rp[row];
    int deg   = rp[row + 1] - start;

    int g = lane >> 3;
    int s = lane & 7;

    float4 acc = make_float4(0.f, 0.f, 0.f, 0.f);

    for (int cb = 0; cb < deg; cb += 64) {
        int rem = deg - cb;
        int nv  = rem < 64 ? rem : 64;
        int myci = (lane < nv) ? ci[start + cb + lane] : 0;
        {
            float4 x[4]; float m[4];
            #pragma unroll
            for (int it = 0; it < 4; ++it) {
                int l = it * 8 + g;
                int c = __shfl(myci, l, 64);
                m[it] = (l < rem) ? 1.f : 0.f;
                x[it] = ((const float4*)(X + (size_t)c * D))[s];
            }
            #pragma unroll
            for (int it = 0; it < 4; ++it) {
                acc.x = fmaf(m[it], x[it].x, acc.x);
                acc.y = fmaf(m[it], x[it].y, acc.y);
                acc.z = fmaf(m[it], x[it].z, acc.z);
                acc.w = fmaf(m[it], x[it].w, acc.w);
            }
        }
        if (rem > 32) {
            float4 x[4]; float m[4];
            #pragma unroll
            for (int it = 0; it < 4; ++it) {
                int l = (it + 4) * 8 + g;
                int c = __shfl(myci, l, 64);
                m[it] = (l < rem) ? 1.f : 0.f;
                x[it] = ((const float4*)(X + (size_t)c * D))[s];
            }
            #pragma unroll
            for (int it = 0; it < 4; ++it) {
                acc.x = fmaf(m[it], x[it].x, acc.x);
                acc.y = fmaf(m[it], x[it].y, acc.y);
                acc.z = fmaf(m[it], x[it].z, acc.z);
                acc.w = fmaf(m[it], x[it].w, acc.w);
            }
        }
    }

    #pragma unroll
    for (int off = 8; off < 64; off <<= 1) {
        acc.x += __shfl_xor(acc.x, off, 64);
        acc.y += __shfl_xor(acc.y, off, 64);
        acc.z += __shfl_xor(acc.z, off, 64);
        acc.w += __shfl_xor(acc.w, off, 64);
    }

    int j = lane & 31;
    float o = 0.f;
    #pragma unroll
    for (int sg = 0; sg < 8; ++sg) {
        float ax = __shfl(acc.x, sg, 64);
        float ay = __shfl(acc.y, sg, 64);
        float az = __shfl(acc.z, sg, 64);
        float aw = __shfl(acc.w, sg, 64);
        int d = 4 * sg;
        o = fmaf(ax, Wl[(d    ) * D + j], o);
        o = fmaf(ay, Wl[(d + 1) * D + j], o);
        o = fmaf(az, Wl[(d + 2) * D + j], o);
        o = fmaf(aw, Wl[(d + 3) * D + j], o);
    }
    if (lane < 32) out[(size_t)row * D + j] = o;
}

extern "C" void kernel_launch(void* const* d_in, const int* in_sizes, int n_in,
                              void* d_out, int out_size, void* d_ws, size_t ws_size,
                              hipStream_t stream) {
    const float* X  = (const float*)d_in[0];
    const float* W  = (const float*)d_in[1];
    const int*   rp = (const int*)d_in[2];
    const int*   ci = (const int*)d_in[3];
    float* out = (float*)d_out;

    int n = in_sizes[2] - 1;                          // N nodes
    size_t ybytes = (size_t)(n + 1) * D * sizeof(float);

    if (ws_size >= ybytes) {
        float* Y = (float*)d_ws;
        int xblocks = (n + 32) / 32;                  // covers rows 0..n
        hipLaunchKernelGGL(xw_kernel, dim3(xblocks), dim3(256), 0, stream,
                           X, W, Y, n);
        int nwaves = (n + 3) / 4;
        int blocks = nwaves < 2048 ? nwaves : 2048;   // persistent waves
        hipLaunchKernelGGL(agg_kernel, dim3(blocks), dim3(256), 0, stream,
                           Y, rp, ci, out, n);
    } else {
        hipLaunchKernelGGL(gin_fused, dim3((n + 3) / 4), dim3(256), 0, stream,
                           X, W, rp, ci, out, n);
    }
}